// Round 1
// baseline (1138.287 us; speedup 1.0000x reference)
//
#include <hip/hip_runtime.h>

typedef unsigned short ush;
typedef __bf16 bf16x8 __attribute__((ext_vector_type(8)));
typedef float f32x4 __attribute__((ext_vector_type(4)));

#define DEVFN __device__ __forceinline__

// bf16 round-to-nearest-even conversion (matches v_cvt semantics for finite vals)
DEVFN ush f2b(float f) {
  unsigned u = __float_as_uint(f);
  return (ush)((u + 0x7FFFu + ((u >> 16) & 1u)) >> 16);
}
DEVFN float b2f(ush v) { return __uint_as_float(((unsigned)v) << 16); }

#define MFMA16(a, b, c) __builtin_amdgcn_mfma_f32_16x16x32_bf16((a), (b), (c), 0, 0, 0)

DEVFN void gl2lds16(const void* g, void* l) {
  __builtin_amdgcn_global_load_lds((__attribute__((address_space(1))) void*)(void*)g,
                                   (__attribute__((address_space(3))) void*)l, 16, 0, 0);
}

// ---------------------------------------------------------------- constants
// B=2 S=2048 E=1024 H=16 D=64; BS=4096 tokens; HD=1024
#define SQ 2048
#define NH 16
#define HD 64

// ---------------------------------------------------------------- prep: fp32 -> bf16 hi/lo splits
struct PrepArgs {
  const float* src[7];
  ush* hi[7];
  ush* lo[7];  // null => single cast only
  int n4[7];
};

__global__ __launch_bounds__(256) void prep_kernel(PrepArgs a) {
  const int seg = blockIdx.y;
  const float4* s = (const float4*)a.src[seg];
  ush* Hp = a.hi[seg];
  ush* Lp = a.lo[seg];
  const int n4 = a.n4[seg];
  for (int i = blockIdx.x * 256 + threadIdx.x; i < n4; i += gridDim.x * 256) {
    float4 v = s[i];
    ush h0 = f2b(v.x), h1 = f2b(v.y), h2 = f2b(v.z), h3 = f2b(v.w);
    ((ushort4*)Hp)[i] = make_ushort4(h0, h1, h2, h3);
    if (Lp) {
      ((ushort4*)Lp)[i] = make_ushort4(f2b(v.x - b2f(h0)), f2b(v.y - b2f(h1)),
                                       f2b(v.z - b2f(h2)), f2b(v.w - b2f(h3)));
    }
  }
}

// ---------------------------------------------------------------- bf16x3 projection GEMM
// C[4096,1024] = A[4096,1024] @ W[1024,1024]^T   (both K-major), acc fp32,
// A,W given as hi/lo bf16 splits; 3 MFMAs per fragment pair (hh + hl + lh).
struct GemmIn {
  const ush *Ah, *Al, *Bh, *Bl;
  ush *Ch, *Cl;  // Cl null => single-bf16 output
};
struct GemmTriple { GemmIn p[3]; };

__global__ __launch_bounds__(256) void proj_gemm_kernel(GemmTriple t3) {
  GemmIn gp = t3.p[blockIdx.z];
  const int mt = blockIdx.x, nt = blockIdx.y;
  __shared__ __align__(16) short Ah[4][128][8], Al[4][128][8], Bh[4][128][8], Bl[4][128][8];
  const int tid = threadIdx.x, w = tid >> 6, lane = tid & 63;
  const int g16 = lane >> 4, c16 = lane & 15;
  const int wr = w >> 1, wc = w & 1;  // 2x2 waves, 64x64 each
  f32x4 acc[4][4] = {};
  for (int kb = 0; kb < 1024; kb += 32) {
    __syncthreads();
    for (int i = 0; i < 2; ++i) {
      int cb = i * 256 + w * 64;  // wave-uniform chunk base
      int c = cb + lane;
      int row = c & 127, k8 = c >> 7;
      size_t ao = (size_t)(mt * 128 + row) * 1024 + kb + k8 * 8;
      size_t bo = (size_t)(nt * 128 + row) * 1024 + kb + k8 * 8;
      gl2lds16(gp.Ah + ao, &Ah[0][0][0] + cb * 8);
      gl2lds16(gp.Al + ao, &Al[0][0][0] + cb * 8);
      gl2lds16(gp.Bh + bo, &Bh[0][0][0] + cb * 8);
      gl2lds16(gp.Bl + bo, &Bl[0][0][0] + cb * 8);
    }
    __syncthreads();
    bf16x8 af[4], al2[4], bf_[4], bl2[4];
    for (int m = 0; m < 4; ++m) {
      af[m]  = *(const bf16x8*)&Ah[g16][wr * 64 + m * 16 + c16][0];
      al2[m] = *(const bf16x8*)&Al[g16][wr * 64 + m * 16 + c16][0];
    }
    for (int n = 0; n < 4; ++n) {
      bf_[n] = *(const bf16x8*)&Bh[g16][wc * 64 + n * 16 + c16][0];
      bl2[n] = *(const bf16x8*)&Bl[g16][wc * 64 + n * 16 + c16][0];
    }
    for (int m = 0; m < 4; ++m)
      for (int n = 0; n < 4; ++n) {
        acc[m][n] = MFMA16(af[m], bf_[n], acc[m][n]);
        acc[m][n] = MFMA16(af[m], bl2[n], acc[m][n]);
        acc[m][n] = MFMA16(al2[m], bf_[n], acc[m][n]);
      }
  }
  const int r0 = mt * 128 + wr * 64, c0 = nt * 128 + wc * 64;
  const bool wantLo = (gp.Cl != nullptr);
  for (int m = 0; m < 4; ++m)
    for (int n = 0; n < 4; ++n)
      for (int r = 0; r < 4; ++r) {
        int row = r0 + m * 16 + g16 * 4 + r;
        int col = c0 + n * 16 + c16;
        size_t idx = (size_t)row * 1024 + col;
        float v = acc[m][n][r];
        ush hv = f2b(v);
        gp.Ch[idx] = hv;
        if (wantLo) gp.Cl[idx] = f2b(v - b2f(hv));
      }
}

// ---------------------------------------------------------------- V transpose: [B,S,H,D] -> [B*H, D, S]
__global__ __launch_bounds__(256) void vtrans_kernel(const ush* __restrict__ vb,
                                                     ush* __restrict__ vt) {
  __shared__ __align__(16) ush T[64][72];
  const int s0 = blockIdx.x * 64, bh = blockIdx.y;
  const int b = bh >> 4, h = bh & 15;
  const int tid = threadIdx.x;
  for (int i = 0; i < 2; ++i) {
    int c = tid + i * 256;
    int s = c >> 3, d8 = c & 7;
    *(uint4*)&T[s][d8 * 8] =
        *(const uint4*)(vb + (size_t)(b * SQ + s0 + s) * 1024 + h * HD + d8 * 8);
  }
  __syncthreads();
  for (int i = 0; i < 2; ++i) {
    int c = tid + i * 256;
    int d = c >> 3, s8 = c & 7;
    ush tmp[8];
    for (int e = 0; e < 8; ++e) tmp[e] = T[s8 * 8 + e][d];
    *(uint4*)(vt + (size_t)(bh * HD + d) * SQ + s0 + s8 * 8) = *(uint4*)tmp;
  }
}

// ---------------------------------------------------------------- A_mem: xpre = g * (elu(q)+1)@M / ((elu(q)+1)@z)
__global__ __launch_bounds__(256) void amem_kernel(const ush* __restrict__ qh,
                                                   const ush* __restrict__ ql,
                                                   const float* __restrict__ M,
                                                   const float* __restrict__ z,
                                                   const float* __restrict__ beta,
                                                   float* __restrict__ xpre) {
  const int wave = (blockIdx.x * 256 + threadIdx.x) >> 6;
  const int lane = threadIdx.x & 63;
  const int nw = (gridDim.x * 256) >> 6;
  for (int r = wave; r < 2 * SQ * NH; r += nw) {  // r = (b*S+s)*H + h
    int h = r & 15;
    float qv = b2f(qh[(size_t)r * 64 + lane]) + b2f(ql[(size_t)r * 64 + lane]);
    float e = qv > 0.f ? qv + 1.f : __expf(qv);
    float dz = e * z[h * 64 + lane];
    for (int off = 32; off; off >>= 1) dz += __shfl_xor(dz, off);
    float acc = 0.f;
    const float* Mh = M + h * 4096;
    for (int j = 0; j < 64; ++j) {
      float ej = __shfl(e, j);
      acc = fmaf(ej, Mh[j * 64 + lane], acc);
    }
    float gate = 1.f / (1.f + __expf(-beta[h]));
    xpre[(size_t)r * 64 + lane] = gate * acc / dz;
  }
}

// ---------------------------------------------------------------- flash: exact softmax (2 passes), ctx write, PV, combine
__global__ __launch_bounds__(256) void flash_kernel(
    const ush* __restrict__ qhp, const ush* __restrict__ qlp,
    const ush* __restrict__ khp, const ush* __restrict__ klp,
    const ush* __restrict__ vtp, const float* __restrict__ beta,
    const float* __restrict__ xpre, ush* __restrict__ xin,
    float* __restrict__ ctx) {
  __shared__ __align__(16) short Ksh[64][72], Ksl[64][72], Vs[64][72];
  __shared__ __align__(16) short Ps[128][72];
  const int bh = blockIdx.y, b = bh >> 4, h = bh & 15;
  const int q0 = blockIdx.x * 128;
  const int tid = threadIdx.x, w = tid >> 6, lane = tid & 63;
  const int g16 = lane >> 4, c16 = lane & 15;

  // resident Q fragments (hi/lo), rows w*32..w*32+32
  bf16x8 qfh[2][2], qfl[2][2];
  for (int m = 0; m < 2; ++m)
    for (int ks = 0; ks < 2; ++ks) {
      int row = q0 + w * 32 + m * 16 + c16;
      size_t off = (size_t)(b * SQ + row) * 1024 + h * HD + ks * 32 + g16 * 8;
      qfh[m][ks] = *(const bf16x8*)(qhp + off);
      qfl[m][ks] = *(const bf16x8*)(qlp + off);
    }
  float mrun[2][4], lrun[2][4];
  for (int m = 0; m < 2; ++m)
    for (int r = 0; r < 4; ++r) { mrun[m][r] = -1e30f; lrun[m][r] = 0.f; }

  // ---- pass 1: exact row max + sum
  for (int t0 = 0; t0 < SQ; t0 += 64) {
    __syncthreads();
    for (int i = 0; i < 2; ++i) {
      int c = tid + i * 256;
      int t = c >> 3, d8 = c & 7;
      size_t go = (size_t)(b * SQ + t0 + t) * 1024 + h * HD + d8 * 8;
      *(uint4*)&Ksh[t][d8 * 8] = *(const uint4*)(khp + go);
      *(uint4*)&Ksl[t][d8 * 8] = *(const uint4*)(klp + go);
    }
    __syncthreads();
    f32x4 acc[2][4] = {};
    for (int ks = 0; ks < 2; ++ks) {
      bf16x8 kh[4], kl[4];
      for (int n = 0; n < 4; ++n) {
        kh[n] = *(const bf16x8*)&Ksh[n * 16 + c16][ks * 32 + g16 * 8];
        kl[n] = *(const bf16x8*)&Ksl[n * 16 + c16][ks * 32 + g16 * 8];
      }
      for (int m = 0; m < 2; ++m)
        for (int n = 0; n < 4; ++n) {
          acc[m][n] = MFMA16(qfh[m][ks], kh[n], acc[m][n]);
          acc[m][n] = MFMA16(qfh[m][ks], kl[n], acc[m][n]);
          acc[m][n] = MFMA16(qfl[m][ks], kh[n], acc[m][n]);
        }
    }
    for (int m = 0; m < 2; ++m)
      for (int r = 0; r < 4; ++r) {
        float mx = fmaxf(fmaxf(acc[m][0][r], acc[m][1][r]),
                         fmaxf(acc[m][2][r], acc[m][3][r])) * 0.125f;
        mx = fmaxf(mx, __shfl_xor(mx, 1));
        mx = fmaxf(mx, __shfl_xor(mx, 2));
        mx = fmaxf(mx, __shfl_xor(mx, 4));
        mx = fmaxf(mx, __shfl_xor(mx, 8));
        float newm = fmaxf(mrun[m][r], mx);
        float sum = 0.f;
        for (int n = 0; n < 4; ++n) sum += __expf(acc[m][n][r] * 0.125f - newm);
        sum += __shfl_xor(sum, 1);
        sum += __shfl_xor(sum, 2);
        sum += __shfl_xor(sum, 4);
        sum += __shfl_xor(sum, 8);
        lrun[m][r] = lrun[m][r] * __expf(mrun[m][r] - newm) + sum;
        mrun[m][r] = newm;
      }
  }
  float linv[2][4];
  for (int m = 0; m < 2; ++m)
    for (int r = 0; r < 4; ++r) linv[m][r] = 1.f / lrun[m][r];
  const float gate = 1.f / (1.f + __expf(-beta[h]));
  const float omg = 1.f - gate;

  // ---- pass 2: p = exp(s-m)/l -> ctx (fp32) + PV
  f32x4 Oacc[2][4] = {};
  for (int t0 = 0; t0 < SQ; t0 += 64) {
    __syncthreads();
    for (int i = 0; i < 2; ++i) {
      int c = tid + i * 256;
      int t = c >> 3, d8 = c & 7;
      size_t go = (size_t)(b * SQ + t0 + t) * 1024 + h * HD + d8 * 8;
      *(uint4*)&Ksh[t][d8 * 8] = *(const uint4*)(khp + go);
      *(uint4*)&Ksl[t][d8 * 8] = *(const uint4*)(klp + go);
      size_t gv = (size_t)(bh * HD + t) * SQ + t0 + d8 * 8;  // Vs[d][t8*8], d=t idx, t8=d8
      *(uint4*)&Vs[t][d8 * 8] = *(const uint4*)(vtp + gv);
    }
    __syncthreads();
    f32x4 acc[2][4] = {};
    for (int ks = 0; ks < 2; ++ks) {
      bf16x8 kh[4], kl[4];
      for (int n = 0; n < 4; ++n) {
        kh[n] = *(const bf16x8*)&Ksh[n * 16 + c16][ks * 32 + g16 * 8];
        kl[n] = *(const bf16x8*)&Ksl[n * 16 + c16][ks * 32 + g16 * 8];
      }
      for (int m = 0; m < 2; ++m)
        for (int n = 0; n < 4; ++n) {
          acc[m][n] = MFMA16(qfh[m][ks], kh[n], acc[m][n]);
          acc[m][n] = MFMA16(qfh[m][ks], kl[n], acc[m][n]);
          acc[m][n] = MFMA16(qfl[m][ks], kh[n], acc[m][n]);
        }
    }
    for (int m = 0; m < 2; ++m)
      for (int n = 0; n < 4; ++n) {
        float pv[4];
        for (int r = 0; r < 4; ++r) {
          float p = __expf(acc[m][n][r] * 0.125f - mrun[m][r]) * linv[m][r];
          pv[r] = p;
          Ps[w * 32 + m * 16 + g16 * 4 + r][n * 16 + c16] = (short)f2b(p);
        }
        for (int r = 0; r < 4; ++r) {
          int qrow = q0 + w * 32 + m * 16 + g16 * 4 + r;
          ctx[((size_t)bh * SQ + qrow) * SQ + t0 + n * 16 + c16] = pv[r];
        }
      }
    for (int ks = 0; ks < 2; ++ks) {
      bf16x8 pa[2], vbv[4];
      for (int m = 0; m < 2; ++m)
        pa[m] = *(const bf16x8*)&Ps[w * 32 + m * 16 + c16][ks * 32 + g16 * 8];
      for (int n = 0; n < 4; ++n)
        vbv[n] = *(const bf16x8*)&Vs[n * 16 + c16][ks * 32 + g16 * 8];
      for (int m = 0; m < 2; ++m)
        for (int n = 0; n < 4; ++n) Oacc[m][n] = MFMA16(pa[m], vbv[n], Oacc[m][n]);
    }
  }
  // combine with gated memory read, emit bf16 input for the output projection
  for (int m = 0; m < 2; ++m)
    for (int n = 0; n < 4; ++n)
      for (int r = 0; r < 4; ++r) {
        int qrow = q0 + w * 32 + m * 16 + g16 * 4 + r;
        int d = n * 16 + c16;
        size_t idx = (size_t)(b * SQ + qrow) * 1024 + h * HD + d;
        xin[idx] = f2b(xpre[idx] + omg * Oacc[m][n][r]);
      }
}

// ---------------------------------------------------------------- output GEMM: out = xin @ Wo^T (bf16, fp32 out)
__global__ __launch_bounds__(256) void final_gemm_kernel(const ush* __restrict__ A,
                                                         const ush* __restrict__ Bw,
                                                         float* __restrict__ out) {
  const int mt = blockIdx.x, nt = blockIdx.y;
  __shared__ __align__(16) short As[4][128][8], Bs[4][64][8];
  const int tid = threadIdx.x, w = tid >> 6, lane = tid & 63;
  const int g16 = lane >> 4, c16 = lane & 15;
  const int wr = w >> 1, wc = w & 1;  // wave tile 64x32
  f32x4 acc[4][2] = {};
  for (int kb = 0; kb < 1024; kb += 32) {
    __syncthreads();
    for (int i = 0; i < 2; ++i) {
      int cb = i * 256 + w * 64;
      int c = cb + lane;
      int row = c & 127, k8 = c >> 7;
      size_t ao = (size_t)(mt * 128 + row) * 1024 + kb + k8 * 8;
      gl2lds16(A + ao, &As[0][0][0] + cb * 8);
    }
    {
      int cb = w * 64;
      int c = cb + lane;
      int row = c & 63, k8 = c >> 6;
      size_t bo = (size_t)(nt * 64 + row) * 1024 + kb + k8 * 8;
      gl2lds16(Bw + bo, &Bs[0][0][0] + cb * 8);
    }
    __syncthreads();
    bf16x8 af[4], bfv[2];
    for (int m = 0; m < 4; ++m)
      af[m] = *(const bf16x8*)&As[g16][wr * 64 + m * 16 + c16][0];
    for (int n = 0; n < 2; ++n)
      bfv[n] = *(const bf16x8*)&Bs[g16][wc * 32 + n * 16 + c16][0];
    for (int m = 0; m < 4; ++m)
      for (int n = 0; n < 2; ++n) acc[m][n] = MFMA16(af[m], bfv[n], acc[m][n]);
  }
  const int r0 = mt * 128 + wr * 64, c0 = nt * 64 + wc * 32;
  for (int m = 0; m < 4; ++m)
    for (int n = 0; n < 2; ++n)
      for (int r = 0; r < 4; ++r) {
        int row = r0 + m * 16 + g16 * 4 + r;
        int col = c0 + n * 16 + c16;
        out[(size_t)row * 1024 + col] = acc[m][n][r];
      }
}

// ---------------------------------------------------------------- host
extern "C" void kernel_launch(void* const* d_in, const int* in_sizes, int n_in,
                              void* d_out, int out_size, void* d_ws, size_t ws_size,
                              hipStream_t stream) {
  (void)in_sizes; (void)n_in; (void)out_size; (void)ws_size;
  const float* query = (const float*)d_in[0];
  const float* key   = (const float*)d_in[1];
  const float* value = (const float*)d_in[2];
  const float* Wq    = (const float*)d_in[3];
  const float* Wk    = (const float*)d_in[4];
  const float* Wv    = (const float*)d_in[5];
  const float* Wo    = (const float*)d_in[6];
  const float* beta  = (const float*)d_in[7];
  const float* mem   = (const float*)d_in[8];
  const float* zv    = (const float*)d_in[9];

  const size_t NQ = 4194304;  // B*S*H*D elements
  const size_t NW = 1048576;  // 1024*1024
  ush* wsp = (ush*)d_ws;
  ush* q_hi  = wsp + 0 * NQ;
  ush* q_lo  = wsp + 1 * NQ;
  ush* k_hi  = wsp + 2 * NQ;
  ush* k_lo  = wsp + 3 * NQ;
  ush* v_b   = wsp + 4 * NQ;
  ush* v_t   = wsp + 5 * NQ;
  ush* sq_hi = wsp + 6 * NQ;
  ush* sq_lo = wsp + 7 * NQ;
  ush* sk_hi = wsp + 8 * NQ;
  ush* sk_lo = wsp + 9 * NQ;
  ush* sv_hi = wsp + 10 * NQ;
  ush* sv_lo = wsp + 11 * NQ;
  ush* wsp2  = wsp + 12 * NQ;
  ush* wq_hi = wsp2 + 0 * NW;
  ush* wq_lo = wsp2 + 1 * NW;
  ush* wk_hi = wsp2 + 2 * NW;
  ush* wk_lo = wsp2 + 3 * NW;
  ush* wv_hi = wsp2 + 4 * NW;
  ush* wv_lo = wsp2 + 5 * NW;
  ush* wo_b  = wsp2 + 6 * NW;
  ush* xin   = wsp2 + 7 * NW;
  float* xpre = (float*)(wsp + 6 * NQ);  // reuses sq_hi/sq_lo after projections
  float* outx = (float*)d_out;
  float* ctx  = outx + 4194304;

  PrepArgs pa;
  pa.src[0] = query; pa.hi[0] = sq_hi; pa.lo[0] = sq_lo; pa.n4[0] = (int)(NQ / 4);
  pa.src[1] = key;   pa.hi[1] = sk_hi; pa.lo[1] = sk_lo; pa.n4[1] = (int)(NQ / 4);
  pa.src[2] = value; pa.hi[2] = sv_hi; pa.lo[2] = sv_lo; pa.n4[2] = (int)(NQ / 4);
  pa.src[3] = Wq;    pa.hi[3] = wq_hi; pa.lo[3] = wq_lo; pa.n4[3] = (int)(NW / 4);
  pa.src[4] = Wk;    pa.hi[4] = wk_hi; pa.lo[4] = wk_lo; pa.n4[4] = (int)(NW / 4);
  pa.src[5] = Wv;    pa.hi[5] = wv_hi; pa.lo[5] = wv_lo; pa.n4[5] = (int)(NW / 4);
  pa.src[6] = Wo;    pa.hi[6] = wo_b;  pa.lo[6] = nullptr; pa.n4[6] = (int)(NW / 4);
  prep_kernel<<<dim3(1024, 7), 256, 0, stream>>>(pa);

  GemmTriple gt;
  gt.p[0] = {sq_hi, sq_lo, wq_hi, wq_lo, q_hi, q_lo};
  gt.p[1] = {sk_hi, sk_lo, wk_hi, wk_lo, k_hi, k_lo};
  gt.p[2] = {sv_hi, sv_lo, wv_hi, wv_lo, v_b, nullptr};
  proj_gemm_kernel<<<dim3(32, 8, 3), 256, 0, stream>>>(gt);

  vtrans_kernel<<<dim3(32, 32), 256, 0, stream>>>(v_b, v_t);
  amem_kernel<<<dim3(512), 256, 0, stream>>>(q_hi, q_lo, mem, zv, beta, xpre);
  flash_kernel<<<dim3(16, 32), 256, 0, stream>>>(q_hi, q_lo, k_hi, k_lo, v_t, beta,
                                                 xpre, xin, ctx);
  final_gemm_kernel<<<dim3(32, 16), 256, 0, stream>>>(xin, wo_b, outx);
}